// Round 7
// baseline (268.504 us; speedup 1.0000x reference)
//
#include <hip/hip_runtime.h>
#include <math.h>

#define B_SZ 4096
#define N_SZ 200
#define K_SZ 64
#define H1 80
#define H2 40
#define NEG_V (-4294967295.0f)

typedef _Float16 f16x8 __attribute__((ext_vector_type(8)));
typedef float f32x4 __attribute__((ext_vector_type(4)));
typedef unsigned int u32;

union H2U { _Float16 h[2]; u32 u; };
union U4F { u32 u[4]; f16x8 v; };

typedef __attribute__((address_space(3))) u32 lds_u32;
typedef const __attribute__((address_space(1))) u32 glb_u32;

__device__ __forceinline__ void gload16(const void* gp, void* lp) {
    __builtin_amdgcn_global_load_lds((glb_u32*)gp, (lds_u32*)lp, 16, 0, 0);
}

// ---------------- qW[b][h] = b1[h] + sum_i q[b][i]*(W1[i][h]+W1[128+i][h])  (exact fp32)
__global__ __launch_bounds__(128) void qw_kernel(const float* __restrict__ query,
                                                 const float* __restrict__ W1,
                                                 const float* __restrict__ b1,
                                                 float* __restrict__ qW) {
    int b = blockIdx.x;
    int tid = threadIdx.x;
    __shared__ float sq[K_SZ];
    if (tid < K_SZ) sq[tid] = query[b * K_SZ + tid];
    __syncthreads();
    if (tid < H1) {
        float acc = b1[tid];
#pragma unroll 8
        for (int i = 0; i < K_SZ; ++i)
            acc += sq[i] * (W1[i * H1 + tid] + W1[(128 + i) * H1 + tid]);
        qW[b * H1 + tid] = acc;
    }
}

// ---------------- pack layer-1/2 weights (A-operand of swapped MFMA), hi|lo interleaved
// frag: lane l, elem j holds W[k = ks*32 + (l>>4)*8 + j][feat = ht*16 + (l&15)]
__global__ __launch_bounds__(256) void prep_bp(const float* __restrict__ W1,
                                               const float* __restrict__ W2,
                                               _Float16* __restrict__ Bp1,
                                               _Float16* __restrict__ Bp2) {
    int idx = blockIdx.x * 256 + threadIdx.x;
    if (idx < 5 * 4 * 64 * 8) {                 // layer1: f = ht*4+ks, 20 frags
        int j = idx & 7, lane = (idx >> 3) & 63, f = idx >> 9;
        int ks = f & 3, ht = f >> 2;
        int k = ks * 32 + (lane >> 4) * 8 + j;  // 0..127: 0-63 k-coef, 64-127 q*k-coef
        int h = ht * 16 + (lane & 15);
        float w = (k < 64) ? (W1[(64 + k) * H1 + h] - W1[(128 + k) * H1 + h])
                           : W1[(192 + (k - 64)) * H1 + h];
        _Float16 hi = (_Float16)w;
        Bp1[(f * 64 + lane) * 16 + j] = hi;
        Bp1[(f * 64 + lane) * 16 + 8 + j] = (_Float16)(w - (float)hi);
    } else {
        int idx2 = idx - 5 * 4 * 64 * 8;
        if (idx2 < 9 * 64 * 8) {                // layer2: f2 = ht2*3+ks2, 9 frags
            int j = idx2 & 7, lane = (idx2 >> 3) & 63, f2 = idx2 >> 9;
            int ks2 = f2 % 3, ht2 = f2 / 3;
            int k2 = ks2 * 32 + (lane >> 4) * 8 + j;
            int m = ht2 * 16 + (lane & 15);
            float w = (k2 < H1 && m < H2) ? W2[k2 * H2 + m] : 0.0f;
            _Float16 hi = (_Float16)w;
            Bp2[(f2 * 64 + lane) * 16 + j] = hi;
            Bp2[(f2 * 64 + lane) * 16 + 8 + j] = (_Float16)(w - (float)hi);
        }
    }
}

// ---------------- fully fused: key DMA->LDS, MLP scores (swapped MFMA), softmax,
// value DMA->LDS (buffer reuse), weighted sum. One b per block, 4 waves.
// key LDS layout: [chunk c=k4][row 0..207][4 f32]  (conflict-free frag reads)
// value LDS layout (reuse): [row 0..199][64 f32]
__global__ __launch_bounds__(256, 2) void fused_kernel(
    const float* __restrict__ query, const float* __restrict__ key,
    const float* __restrict__ value, const int* __restrict__ mask,
    const _Float16* __restrict__ Bp1, const _Float16* __restrict__ Bp2,
    const float* __restrict__ a1, const float* __restrict__ b2,
    const float* __restrict__ a2, const float* __restrict__ Wo,
    const float* __restrict__ bo, const float* __restrict__ qW,
    float* __restrict__ out) {
    __shared__ float kbuf[13312];      // 53,248 B
    __shared__ float sq[K_SZ];
    __shared__ float sqW[H1];
    __shared__ float sa1[H1];
    __shared__ float sb2[48], sa2[48], sWo[48];
    __shared__ int   smask[208];
    __shared__ float sprob[256];
    __shared__ float sred[8];
    __shared__ float spart[4 * K_SZ];

    const int tid = threadIdx.x;
    const int wv = tid >> 6;
    const int l = tid & 63;
    const int l15 = l & 15;
    const int lg = l >> 4;
    const int b = blockIdx.x;
    const int p0 = b * N_SZ;
    const int tb = (wv == 0) ? 0 : 1 + wv * 3;   // first tile; counts {4,3,3,3}

    // ---- issue key DMA first: 3328 16B-chunks, wave covers [wv*832, +832)
    {
        int g0 = wv * 832;
#pragma unroll
        for (int i = 0; i < 13; ++i) {
            int g = g0 + i * 64 + l;
            int row = g % 208;
            int c = g / 208;
            int rc = (row < N_SZ) ? row : (N_SZ - 1);
            gload16(&key[((size_t)(p0 + rc)) * K_SZ + c * 4], &kbuf[(g0 + i * 64) * 4]);
        }
    }

    // ---- stage params
    if (tid < K_SZ) sq[tid] = query[b * K_SZ + tid];
    if (tid < H1) { sqW[tid] = qW[b * H1 + tid]; sa1[tid] = a1[tid]; }
    if (tid >= 128 && tid < 176) {
        int i = tid - 128;
        sb2[i] = (i < H2) ? b2[i] : 0.0f;
        sa2[i] = (i < H2) ? a2[i] : 0.0f;
        sWo[i] = (i < H2) ? Wo[i] : 0.0f;
    }
    for (int i = tid; i < 208; i += 256) smask[i] = (i < N_SZ) ? mask[p0 + i] : 0;
    float bov = bo[0];
    __syncthreads();   // drains key DMA (vmcnt(0) before barrier)

    // ---- compute 13 tiles in groups of <=2 per wave
    for (int g = 0; g < 2; ++g) {
        const int ta = tb + g * 2;
        const bool v1 = (g == 0) || (wv == 0);   // slot-1 validity

        // features from LDS -> fp16 frags
        f16x8 Bk[2][2], Bqk[2][2];
#pragma unroll
        for (int i = 0; i < 2; ++i) {
            if (i == 0 || v1) {
                int trow = (ta + i) * 16 + l15;
#pragma unroll
                for (int ksp = 0; ksp < 2; ++ksp) {
                    int c0 = ksp * 8 + lg * 2;
                    float4 k0 = *reinterpret_cast<const float4*>(&kbuf[(c0 * 208 + trow) * 4]);
                    float4 k1 = *reinterpret_cast<const float4*>(&kbuf[((c0 + 1) * 208 + trow) * 4]);
                    float4 q0 = *reinterpret_cast<const float4*>(&sq[ksp * 32 + lg * 8]);
                    float4 q1 = *reinterpret_cast<const float4*>(&sq[ksp * 32 + lg * 8 + 4]);
                    f16x8 bk, bq;
                    bk[0] = (_Float16)k0.x; bk[1] = (_Float16)k0.y; bk[2] = (_Float16)k0.z; bk[3] = (_Float16)k0.w;
                    bk[4] = (_Float16)k1.x; bk[5] = (_Float16)k1.y; bk[6] = (_Float16)k1.z; bk[7] = (_Float16)k1.w;
                    bq[0] = (_Float16)(q0.x * k0.x); bq[1] = (_Float16)(q0.y * k0.y);
                    bq[2] = (_Float16)(q0.z * k0.z); bq[3] = (_Float16)(q0.w * k0.w);
                    bq[4] = (_Float16)(q1.x * k1.x); bq[5] = (_Float16)(q1.y * k1.y);
                    bq[6] = (_Float16)(q1.z * k1.z); bq[7] = (_Float16)(q1.w * k1.w);
                    Bk[i][ksp] = bk; Bqk[i][ksp] = bq;
                }
            }
        }

        // layer 1
        f32x4 acc[2][5];
#pragma unroll
        for (int i = 0; i < 2; ++i)
#pragma unroll
            for (int ht = 0; ht < 5; ++ht) acc[i][ht] = (f32x4){0.f, 0.f, 0.f, 0.f};
#pragma unroll
        for (int ht = 0; ht < 5; ++ht) {
#pragma unroll
            for (int kk = 0; kk < 4; ++kk) {       // kk<2: k-part, kk>=2: q*k-part
                int fidx = (ht * 4 + kk) * 64 + l;
                f16x8 wh = *reinterpret_cast<const f16x8*>(&Bp1[fidx * 16]);
                f16x8 wl = *reinterpret_cast<const f16x8*>(&Bp1[fidx * 16 + 8]);
                f16x8 f0 = (kk < 2) ? Bk[0][kk & 1] : Bqk[0][kk & 1];
                acc[0][ht] = __builtin_amdgcn_mfma_f32_16x16x32_f16(wh, f0, acc[0][ht], 0, 0, 0);
                acc[0][ht] = __builtin_amdgcn_mfma_f32_16x16x32_f16(wl, f0, acc[0][ht], 0, 0, 0);
                if (v1) {
                    f16x8 f1 = (kk < 2) ? Bk[1][kk & 1] : Bqk[1][kk & 1];
                    acc[1][ht] = __builtin_amdgcn_mfma_f32_16x16x32_f16(wh, f1, acc[1][ht], 0, 0, 0);
                    acc[1][ht] = __builtin_amdgcn_mfma_f32_16x16x32_f16(wl, f1, acc[1][ht], 0, 0, 0);
                }
            }
        }

        // epilogue 1: prelu(D1 + qW) -> packed fp16
        u32 pk[2][6][2];
#pragma unroll
        for (int i = 0; i < 2; ++i) {
            if (i == 0 || v1) {
#pragma unroll
                for (int ht = 0; ht < 5; ++ht) {
                    float4 qw4 = *reinterpret_cast<const float4*>(&sqW[ht * 16 + lg * 4]);
                    float4 aa4 = *reinterpret_cast<const float4*>(&sa1[ht * 16 + lg * 4]);
                    float h0 = acc[i][ht][0] + qw4.x;
                    float h1v = acc[i][ht][1] + qw4.y;
                    float h2 = acc[i][ht][2] + qw4.z;
                    float h3 = acc[i][ht][3] + qw4.w;
                    h0 = (h0 > 0.f) ? h0 : h0 * aa4.x;
                    h1v = (h1v > 0.f) ? h1v : h1v * aa4.y;
                    h2 = (h2 > 0.f) ? h2 : h2 * aa4.z;
                    h3 = (h3 > 0.f) ? h3 : h3 * aa4.w;
                    H2U u0, u1;
                    u0.h[0] = (_Float16)h0; u0.h[1] = (_Float16)h1v;
                    u1.h[0] = (_Float16)h2; u1.h[1] = (_Float16)h3;
                    pk[i][ht][0] = u0.u;
                    pk[i][ht][1] = u1.u;
                }
                pk[i][5][0] = 0u; pk[i][5][1] = 0u;
            }
        }

        // layer 2
        f32x4 acc2[2][3];
#pragma unroll
        for (int i = 0; i < 2; ++i)
#pragma unroll
            for (int ht = 0; ht < 3; ++ht) acc2[i][ht] = (f32x4){0.f, 0.f, 0.f, 0.f};
#pragma unroll
        for (int ks2 = 0; ks2 < 3; ++ks2) {
            f16x8 B2f[2];
#pragma unroll
            for (int i = 0; i < 2; ++i) {
                if (i == 0 || v1) {
                    U4F bu;
#pragma unroll
                    for (int q = 0; q < 4; ++q) {
                        int src = ((lg * 2 + (q >> 1)) & 3) * 16 + l15;
                        u32 va = (u32)__shfl((int)pk[i][ks2 * 2][q & 1], src, 64);
                        u32 vb = (u32)__shfl((int)pk[i][ks2 * 2 + 1][q & 1], src, 64);
                        bu.u[q] = (lg < 2) ? va : vb;
                    }
                    B2f[i] = bu.v;
                }
            }
#pragma unroll
            for (int ht2 = 0; ht2 < 3; ++ht2) {
                int fidx = (ht2 * 3 + ks2) * 64 + l;
                f16x8 wh = *reinterpret_cast<const f16x8*>(&Bp2[fidx * 16]);
                f16x8 wl = *reinterpret_cast<const f16x8*>(&Bp2[fidx * 16 + 8]);
                acc2[0][ht2] = __builtin_amdgcn_mfma_f32_16x16x32_f16(wh, B2f[0], acc2[0][ht2], 0, 0, 0);
                acc2[0][ht2] = __builtin_amdgcn_mfma_f32_16x16x32_f16(wl, B2f[0], acc2[0][ht2], 0, 0, 0);
                if (v1) {
                    acc2[1][ht2] = __builtin_amdgcn_mfma_f32_16x16x32_f16(wh, B2f[1], acc2[1][ht2], 0, 0, 0);
                    acc2[1][ht2] = __builtin_amdgcn_mfma_f32_16x16x32_f16(wl, B2f[1], acc2[1][ht2], 0, 0, 0);
                }
            }
        }

        // epilogue 2 + layer 3
#pragma unroll
        for (int i = 0; i < 2; ++i) {
            if (i == 0 || v1) {
                float psum = 0.f;
#pragma unroll
                for (int ht2 = 0; ht2 < 3; ++ht2) {
                    float4 b4 = *reinterpret_cast<const float4*>(&sb2[ht2 * 16 + lg * 4]);
                    float4 a4 = *reinterpret_cast<const float4*>(&sa2[ht2 * 16 + lg * 4]);
                    float4 w4 = *reinterpret_cast<const float4*>(&sWo[ht2 * 16 + lg * 4]);
                    float v0 = acc2[i][ht2][0] + b4.x;
                    float v1f = acc2[i][ht2][1] + b4.y;
                    float v2 = acc2[i][ht2][2] + b4.z;
                    float v3 = acc2[i][ht2][3] + b4.w;
                    v0 = (v0 > 0.f) ? v0 : v0 * a4.x;
                    v1f = (v1f > 0.f) ? v1f : v1f * a4.y;
                    v2 = (v2 > 0.f) ? v2 : v2 * a4.z;
                    v3 = (v3 > 0.f) ? v3 : v3 * a4.w;
                    psum += v0 * w4.x + v1f * w4.y + v2 * w4.z + v3 * w4.w;
                }
                psum += __shfl_xor(psum, 16);
                psum += __shfl_xor(psum, 32);
                if (lg == 0) {
                    int nloc = (ta + i) * 16 + l15;
                    sprob[nloc] = (nloc < N_SZ) ? ((smask[nloc] == 0) ? NEG_V : (psum + bov))
                                                : -INFINITY;
                }
            }
        }
    }
    __syncthreads();   // (1) all scores staged; all key LDS reads complete

    // ---- issue value DMA into kbuf (row-major [200][64]): 3200 chunks
    {
        int g0v = wv * 800;
#pragma unroll
        for (int i = 0; i < 13; ++i) {
            if (i * 64 + l < 800) {
                int g = g0v + i * 64 + l;
                int row = g >> 4, cc = g & 15;
                gload16(&value[((size_t)(p0 + row)) * K_SZ + cc * 4], &kbuf[(g0v + i * 64) * 4]);
            }
        }
    }

    // ---- softmax over 208 (pads -inf); overlaps value DMA
    float s = (tid < 208) ? sprob[tid] : -INFINITY;
    float m = s;
#pragma unroll
    for (int off = 32; off >= 1; off >>= 1) m = fmaxf(m, __shfl_xor(m, off));
    if ((tid & 63) == 0) sred[tid >> 6] = m;
    __syncthreads();   // (2) also drains value DMA
    m = fmaxf(fmaxf(sred[0], sred[1]), fmaxf(sred[2], sred[3]));

    float e = (tid < 208) ? expf(s - m) : 0.0f;
    sprob[tid] = e;
    float t = e;
#pragma unroll
    for (int off = 32; off >= 1; off >>= 1) t += __shfl_xor(t, off);
    if ((tid & 63) == 0) sred[4 + (tid >> 6)] = t;
    __syncthreads();   // (3)
    float inv = 1.0f / (sred[4] + sred[5] + sred[6] + sred[7]);

    // ---- weighted value sum from LDS: wave wv covers rows [50wv, 50wv+50)
    float acc0 = 0.0f, acc1v = 0.0f;
#pragma unroll 5
    for (int jj = 0; jj < 50; jj += 2) {
        int n = wv * 50 + jj;
        acc0  += sprob[n]     * kbuf[n * 64 + l];
        acc1v += sprob[n + 1] * kbuf[(n + 1) * 64 + l];
    }
    spart[wv * K_SZ + l] = acc0 + acc1v;
    __syncthreads();   // (4)
    if (tid < K_SZ) {
        out[b * K_SZ + tid] =
            (spart[tid] + spart[64 + tid] + spart[128 + tid] + spart[192 + tid]) * inv;
    }
}

extern "C" void kernel_launch(void* const* d_in, const int* in_sizes, int n_in,
                              void* d_out, int out_size, void* d_ws, size_t ws_size,
                              hipStream_t stream) {
    const float* query = (const float*)d_in[0];
    const float* key   = (const float*)d_in[1];
    const float* value = (const float*)d_in[2];
    const int*   mask  = (const int*)d_in[3];
    const float* W1    = (const float*)d_in[4];
    const float* b1    = (const float*)d_in[5];
    const float* a1    = (const float*)d_in[6];
    const float* W2    = (const float*)d_in[7];
    const float* b2    = (const float*)d_in[8];
    const float* a2    = (const float*)d_in[9];
    const float* Wo    = (const float*)d_in[10];
    const float* bo    = (const float*)d_in[11];
    float* out = (float*)d_out;

    float* qW     = (float*)d_ws;                        // B*H1 floats
    _Float16* Bp1 = (_Float16*)(qW + (size_t)B_SZ * H1); // 20*64*16 halves
    _Float16* Bp2 = Bp1 + 20 * 64 * 16;                  // 9*64*16 halves

    qw_kernel<<<B_SZ, 128, 0, stream>>>(query, W1, b1, qW);
    prep_bp<<<58, 256, 0, stream>>>(W1, W2, Bp1, Bp2);
    fused_kernel<<<B_SZ, 256, 0, stream>>>(
        query, key, value, mask, Bp1, Bp2, a1, b2, a2, Wo, bo, qW, out);
}

// Round 10
// 155.648 us; speedup vs baseline: 1.7251x; 1.7251x over previous
//
#include <hip/hip_runtime.h>
#include <math.h>

#define B_SZ 4096
#define N_SZ 200
#define K_SZ 64
#define H1 80
#define H2 40
#define NEG_V (-4294967295.0f)

#define NFRAG 29          // 20 layer-1 frags + 9 layer-2 frags
#define WHALVES (NFRAG * 1024)   // halves in weight image (2 KB per frag)

typedef _Float16 f16x8 __attribute__((ext_vector_type(8)));
typedef float f32x4 __attribute__((ext_vector_type(4)));
typedef unsigned int u32;

union H2U { _Float16 h[2]; u32 u; };
union U4F { u32 u[4]; f16x8 v; };

typedef __attribute__((address_space(3))) u32 lds_u32;
typedef const __attribute__((address_space(1))) u32 glb_u32;

__device__ __forceinline__ void gload16(const void* gp, void* lp) {
    __builtin_amdgcn_global_load_lds((glb_u32*)gp, (lds_u32*)lp, 16, 0, 0);
}

// ---------------- qW[b][h] = b1[h] + sum_i q[b][i]*(W1[i][h]+W1[128+i][h])  (exact fp32)
__global__ __launch_bounds__(128) void qw_kernel(const float* __restrict__ query,
                                                 const float* __restrict__ W1,
                                                 const float* __restrict__ b1,
                                                 float* __restrict__ qW) {
    int b = blockIdx.x;
    int tid = threadIdx.x;
    __shared__ float sq[K_SZ];
    if (tid < K_SZ) sq[tid] = query[b * K_SZ + tid];
    __syncthreads();
    if (tid < H1) {
        float acc = b1[tid];
#pragma unroll 8
        for (int i = 0; i < K_SZ; ++i)
            acc += sq[i] * (W1[i * H1 + tid] + W1[(128 + i) * H1 + tid]);
        qW[b * H1 + tid] = acc;
    }
}

// ---------------- pack weights into the LDS image order (bank-swizzled, hi|lo 16B halves)
// frag f: lane l, elem j holds W[k = ks*32 + (l>>4)*8 + j][feat = ht*16 + (l&15)]
// image byte for (f,l,s=hi0/lo1): f*2048 + ((l*32 + s*16) ^ (((l>>2)&3)<<4)) + j*2
__global__ __launch_bounds__(256) void prep_bp(const float* __restrict__ W1,
                                               const float* __restrict__ W2,
                                               _Float16* __restrict__ Bp) {
    int idx = blockIdx.x * 256 + threadIdx.x;
    if (idx >= NFRAG * 512) return;
    int j = idx & 7, lane = (idx >> 3) & 63, f = idx >> 9;
    float w;
    if (f < 20) {                       // layer1: f = ht*4+ks
        int ks = f & 3, ht = f >> 2;
        int k = ks * 32 + (lane >> 4) * 8 + j;   // 0-63 k-coef, 64-127 q*k-coef
        int h = ht * 16 + (lane & 15);
        w = (k < 64) ? (W1[(64 + k) * H1 + h] - W1[(128 + k) * H1 + h])
                     : W1[(192 + (k - 64)) * H1 + h];
    } else {                            // layer2: f-20 = ht2*3+ks2
        int f2 = f - 20;
        int ks2 = f2 % 3, ht2 = f2 / 3;
        int k2 = ks2 * 32 + (lane >> 4) * 8 + j;
        int m = ht2 * 16 + (lane & 15);
        w = (k2 < H1 && m < H2) ? W2[k2 * H2 + m] : 0.0f;
    }
    _Float16 hi = (_Float16)w;
    _Float16 lo = (_Float16)(w - (float)hi);
    int swq = ((lane >> 2) & 3) << 4;
    int base = f * 1024;                // halves
    Bp[base + (((lane * 32) ^ swq) >> 1) + j] = hi;
    Bp[base + (((lane * 32 + 16) ^ swq) >> 1) + j] = lo;
}

// ---------------- fully fused: weights DMA->LDS once, MLP scores (swapped MFMA),
// masked softmax, value-weighted sum. One b per block, 4 waves, tiles {4,3,3,3}.
__global__ __launch_bounds__(256, 2) void fused_kernel(
    const float* __restrict__ query, const float* __restrict__ key,
    const float* __restrict__ value, const int* __restrict__ mask,
    const _Float16* __restrict__ BpG,
    const float* __restrict__ a1, const float* __restrict__ b2,
    const float* __restrict__ a2, const float* __restrict__ Wo,
    const float* __restrict__ bo, const float* __restrict__ qW,
    float* __restrict__ out) {
    __shared__ _Float16 wlds[WHALVES];   // 59,392 B weight image
    __shared__ float sq[K_SZ];
    __shared__ float sqW[H1];
    __shared__ float sa1[H1];
    __shared__ float sb2[48], sa2[48], sWo[48];
    __shared__ float sprob[256];
    __shared__ float sred[8];
    __shared__ float spart[4 * K_SZ];

    const int tid = threadIdx.x;
    const int wv = tid >> 6;
    const int l = tid & 63;
    const int l15 = l & 15;
    const int lg = l >> 4;
    const int b = blockIdx.x;
    const int p0 = b * N_SZ;
    const int NT = (wv == 0) ? 4 : 3;
    const int tb = (wv == 0) ? 0 : 1 + wv * 3;

    // ---- stage weight image: 3712 16B chunks, coalesced DMA, linear dest
    {
#pragma unroll
        for (int i = 0; i < 14; ++i) {
            int cb = i * 256 + wv * 64;              // wave-uniform chunk base
            gload16(&BpG[(size_t)(cb + l) * 8], (char*)wlds + (size_t)cb * 16);
        }
        if (wv < 2) {                                // tail 128 chunks, whole waves
            int cb = 3584 + wv * 64;
            gload16(&BpG[(size_t)(cb + l) * 8], (char*)wlds + (size_t)cb * 16);
        }
    }

    // ---- stage params
    if (tid < K_SZ) sq[tid] = query[b * K_SZ + tid];
    if (tid < H1) { sqW[tid] = qW[b * H1 + tid]; sa1[tid] = a1[tid]; }
    if (tid >= 128 && tid < 176) {
        int i = tid - 128;
        sb2[i] = (i < H2) ? b2[i] : 0.0f;
        sa2[i] = (i < H2) ? a2[i] : 0.0f;
        sWo[i] = (i < H2) ? Wo[i] : 0.0f;
    }
    float bov = bo[0];
    __syncthreads();    // drains weight DMA (vmcnt(0) before barrier)

    // per-lane swizzled weight offsets (halves)
    const int swq = ((l >> 2) & 3) << 4;
    const int offh = ((l * 32) ^ swq) >> 1;
    const int offl = ((l * 32 + 16) ^ swq) >> 1;

    // ---- layer 1: D1[f][n] = sum_k W1c[k][f] * F[k][n]
    f32x4 D1[4][5];
#pragma unroll
    for (int i = 0; i < 4; ++i)
#pragma unroll
        for (int ht = 0; ht < 5; ++ht) D1[i][ht] = (f32x4){0.f, 0.f, 0.f, 0.f};

#pragma unroll
    for (int ksp = 0; ksp < 2; ++ksp) {
        const float* qp = &sq[ksp * 32 + lg * 8];
        float4 q0 = *reinterpret_cast<const float4*>(qp);
        float4 q1 = *reinterpret_cast<const float4*>(qp + 4);
        f16x8 Bk[4], Bqk[4];
#pragma unroll
        for (int i = 0; i < 4; ++i) {
            if (i < NT) {
                int nloc = (tb + i) * 16 + l15;
                int pg = p0 + nloc;
                int pgc = (pg < B_SZ * N_SZ) ? pg : (B_SZ * N_SZ - 1);
                const float* kp = &key[(size_t)pgc * K_SZ + ksp * 32 + lg * 8];
                float4 k0 = *reinterpret_cast<const float4*>(kp);
                float4 k1 = *reinterpret_cast<const float4*>(kp + 4);
                f16x8 bk, bq;
                bk[0] = (_Float16)k0.x; bk[1] = (_Float16)k0.y; bk[2] = (_Float16)k0.z; bk[3] = (_Float16)k0.w;
                bk[4] = (_Float16)k1.x; bk[5] = (_Float16)k1.y; bk[6] = (_Float16)k1.z; bk[7] = (_Float16)k1.w;
                bq[0] = (_Float16)(q0.x * k0.x); bq[1] = (_Float16)(q0.y * k0.y);
                bq[2] = (_Float16)(q0.z * k0.z); bq[3] = (_Float16)(q0.w * k0.w);
                bq[4] = (_Float16)(q1.x * k1.x); bq[5] = (_Float16)(q1.y * k1.y);
                bq[6] = (_Float16)(q1.z * k1.z); bq[7] = (_Float16)(q1.w * k1.w);
                Bk[i] = bk; Bqk[i] = bq;
            }
        }
#pragma unroll
        for (int ht = 0; ht < 5; ++ht) {
#pragma unroll
            for (int s = 0; s < 2; ++s) {
                int kk = ksp + s * 2;                 // weight k-tile index
                int fb = (ht * 4 + kk) * 1024;
                f16x8 wh = *reinterpret_cast<const f16x8*>(&wlds[fb + offh]);
                f16x8 wl = *reinterpret_cast<const f16x8*>(&wlds[fb + offl]);
#pragma unroll
                for (int i = 0; i < 4; ++i) {
                    if (i < NT) {
                        f16x8 bb = (s == 0) ? Bk[i] : Bqk[i];
                        D1[i][ht] = __builtin_amdgcn_mfma_f32_16x16x32_f16(wh, bb, D1[i][ht], 0, 0, 0);
                        D1[i][ht] = __builtin_amdgcn_mfma_f32_16x16x32_f16(wl, bb, D1[i][ht], 0, 0, 0);
                    }
                }
            }
        }
    }

    // ---- epilogue 1 (in-register): h1 = prelu(D1 + qW), pack to fp16 pairs
    u32 pk[4][6][2];
#pragma unroll
    for (int i = 0; i < 4; ++i) {
        if (i < NT) {
#pragma unroll
            for (int ht = 0; ht < 5; ++ht) {
                float4 qw4 = *reinterpret_cast<const float4*>(&sqW[ht * 16 + lg * 4]);
                float4 aa4 = *reinterpret_cast<const float4*>(&sa1[ht * 16 + lg * 4]);
                float h0 = D1[i][ht][0] + qw4.x;
                float h1v = D1[i][ht][1] + qw4.y;
                float h2 = D1[i][ht][2] + qw4.z;
                float h3 = D1[i][ht][3] + qw4.w;
                h0 = (h0 > 0.f) ? h0 : h0 * aa4.x;
                h1v = (h1v > 0.f) ? h1v : h1v * aa4.y;
                h2 = (h2 > 0.f) ? h2 : h2 * aa4.z;
                h3 = (h3 > 0.f) ? h3 : h3 * aa4.w;
                H2U u0, u1;
                u0.h[0] = (_Float16)h0; u0.h[1] = (_Float16)h1v;
                u1.h[0] = (_Float16)h2; u1.h[1] = (_Float16)h3;
                pk[i][ht][0] = u0.u;
                pk[i][ht][1] = u1.u;
            }
            pk[i][5][0] = 0u; pk[i][5][1] = 0u;   // zero-pad feats 80..95
        }
    }

    // ---- layer 2: D2[m][n] = sum_k2 W2[k2][m] * h1[k2][n]
    f32x4 D2[4][3];
#pragma unroll
    for (int i = 0; i < 4; ++i)
#pragma unroll
        for (int ht = 0; ht < 3; ++ht) D2[i][ht] = (f32x4){0.f, 0.f, 0.f, 0.f};

#pragma unroll
    for (int ks2 = 0; ks2 < 3; ++ks2) {
        f16x8 B2f[4];
#pragma unroll
        for (int i = 0; i < 4; ++i) {
            if (i < NT) {
                U4F bu;
#pragma unroll
                for (int q = 0; q < 4; ++q) {
                    int src = ((lg * 2 + (q >> 1)) & 3) * 16 + l15;
                    u32 va = (u32)__shfl((int)pk[i][ks2 * 2][q & 1], src, 64);
                    u32 vb = (u32)__shfl((int)pk[i][ks2 * 2 + 1][q & 1], src, 64);
                    bu.u[q] = (lg < 2) ? va : vb;
                }
                B2f[i] = bu.v;
            }
        }
#pragma unroll
        for (int ht2 = 0; ht2 < 3; ++ht2) {
            int fb = (20 + ht2 * 3 + ks2) * 1024;
            f16x8 wh = *reinterpret_cast<const f16x8*>(&wlds[fb + offh]);
            f16x8 wl = *reinterpret_cast<const f16x8*>(&wlds[fb + offl]);
#pragma unroll
            for (int i = 0; i < 4; ++i) {
                if (i < NT) {
                    D2[i][ht2] = __builtin_amdgcn_mfma_f32_16x16x32_f16(wh, B2f[i], D2[i][ht2], 0, 0, 0);
                    D2[i][ht2] = __builtin_amdgcn_mfma_f32_16x16x32_f16(wl, B2f[i], D2[i][ht2], 0, 0, 0);
                }
            }
        }
    }

    // ---- epilogue 2 + layer 3: score(n) = bo + sum_m Wo[m]*prelu(D2[m][n]+b2[m])
#pragma unroll
    for (int i = 0; i < 4; ++i) {
        if (i < NT) {
            float psum = 0.f;
#pragma unroll
            for (int ht2 = 0; ht2 < 3; ++ht2) {
                float4 b4 = *reinterpret_cast<const float4*>(&sb2[ht2 * 16 + lg * 4]);
                float4 a4 = *reinterpret_cast<const float4*>(&sa2[ht2 * 16 + lg * 4]);
                float4 w4 = *reinterpret_cast<const float4*>(&sWo[ht2 * 16 + lg * 4]);
                float v0 = D2[i][ht2][0] + b4.x;
                float v1 = D2[i][ht2][1] + b4.y;
                float v2 = D2[i][ht2][2] + b4.z;
                float v3 = D2[i][ht2][3] + b4.w;
                v0 = (v0 > 0.f) ? v0 : v0 * a4.x;
                v1 = (v1 > 0.f) ? v1 : v1 * a4.y;
                v2 = (v2 > 0.f) ? v2 : v2 * a4.z;
                v3 = (v3 > 0.f) ? v3 : v3 * a4.w;
                psum += v0 * w4.x + v1 * w4.y + v2 * w4.z + v3 * w4.w;
            }
            psum += __shfl_xor(psum, 16);
            psum += __shfl_xor(psum, 32);
            if (lg == 0) {
                int nloc = (tb + i) * 16 + l15;
                float sv;
                if (nloc < N_SZ) sv = (mask[p0 + nloc] == 0) ? NEG_V : (psum + bov);
                else sv = -INFINITY;
                sprob[nloc] = sv;
            }
        }
    }
    __syncthreads();

    // ---- softmax over the 208 staged scores (pads are -inf)
    float s = (tid < 208) ? sprob[tid] : -INFINITY;
    float m = s;
#pragma unroll
    for (int off = 32; off >= 1; off >>= 1) m = fmaxf(m, __shfl_xor(m, off));
    if ((tid & 63) == 0) sred[tid >> 6] = m;
    __syncthreads();
    m = fmaxf(fmaxf(sred[0], sred[1]), fmaxf(sred[2], sred[3]));

    float e = (tid < 208) ? expf(s - m) : 0.0f;
    sprob[tid] = e;
    float t = e;
#pragma unroll
    for (int off = 32; off >= 1; off >>= 1) t += __shfl_xor(t, off);
    if ((tid & 63) == 0) sred[4 + (tid >> 6)] = t;
    __syncthreads();
    float inv = 1.0f / (sred[4] + sred[5] + sred[6] + sred[7]);

    // ---- weighted value sum: wave wv covers n = [50wv, 50wv+50), lane = k index
    float acc0 = 0.0f, acc1v = 0.0f;
#pragma unroll 5
    for (int jj = 0; jj < 50; jj += 2) {
        int n = wv * 50 + jj;
        acc0  += sprob[n]     * value[((size_t)p0 + n)     * K_SZ + l];
        acc1v += sprob[n + 1] * value[((size_t)p0 + n + 1) * K_SZ + l];
    }
    spart[wv * K_SZ + l] = acc0 + acc1v;
    __syncthreads();
    if (tid < K_SZ) {
        out[b * K_SZ + tid] =
            (spart[tid] + spart[64 + tid] + spart[128 + tid] + spart[192 + tid]) * inv;
    }
}

extern "C" void kernel_launch(void* const* d_in, const int* in_sizes, int n_in,
                              void* d_out, int out_size, void* d_ws, size_t ws_size,
                              hipStream_t stream) {
    const float* query = (const float*)d_in[0];
    const float* key   = (const float*)d_in[1];
    const float* value = (const float*)d_in[2];
    const int*   mask  = (const int*)d_in[3];
    const float* W1    = (const float*)d_in[4];
    const float* b1    = (const float*)d_in[5];
    const float* a1    = (const float*)d_in[6];
    const float* W2    = (const float*)d_in[7];
    const float* b2    = (const float*)d_in[8];
    const float* a2    = (const float*)d_in[9];
    const float* Wo    = (const float*)d_in[10];
    const float* bo    = (const float*)d_in[11];
    float* out = (float*)d_out;

    float* qW    = (float*)d_ws;                         // B*H1 floats
    _Float16* Bp = (_Float16*)(qW + (size_t)B_SZ * H1);  // NFRAG*1024 halves

    qw_kernel<<<B_SZ, 128, 0, stream>>>(query, W1, b1, qW);
    prep_bp<<<(NFRAG * 512 + 255) / 256, 256, 0, stream>>>(W1, W2, Bp);
    fused_kernel<<<B_SZ, 256, 0, stream>>>(
        query, key, value, mask, Bp, a1, b2, a2, Wo, bo, qW, out);
}